// Round 3
// baseline (127.219 us; speedup 1.0000x reference)
//
#include <hip/hip_runtime.h>

#define MASK_HW 28
#define OUT_H 512
#define OUT_W 512
#define N_INST 100
#define ROWS_PER_TILE 16

typedef __attribute__((ext_vector_type(4))) float f32x4;

// ---------------------------------------------------------------------------
// Kernel Z: memset-clone. Exact grid, one nontemporal float4 store per
// thread, no loop, minimal VGPRs. nt flag avoids write-allocating into the
// poison-dirtied LLC.
// ---------------------------------------------------------------------------
__global__ __launch_bounds__(256) void zero_fill_kernel(f32x4* __restrict__ out)
{
    const int i = blockIdx.x * 256 + threadIdx.x;
    f32x4 z = (f32x4)0.0f;
    __builtin_nontemporal_store(z, out + i);
}

// ---------------------------------------------------------------------------
// Kernel B: bilinear paste only inside each instance's box rectangle.
// Grid: (instance, row-tile); out-of-range tiles exit immediately.
// ---------------------------------------------------------------------------
__global__ __launch_bounds__(256) void paste_box_kernel(
    const float* __restrict__ masks,   // [N,1,28,28]
    const float* __restrict__ boxes,   // [N,4]
    float* __restrict__ out)           // [N,1,512,512]
{
    const int n   = blockIdx.x;
    const int tid = threadIdx.x;

    const float bx0 = boxes[4 * n + 0];
    const float by0 = boxes[4 * n + 1];
    const float bx1 = boxes[4 * n + 2] + 1e-5f;
    const float by1 = boxes[4 * n + 3] + 1e-5f;
    const float sxf = 28.0f / (bx1 - bx0);
    const float syf = 28.0f / (by1 - by0);
    const float inv_sx = (bx1 - bx0) * (1.0f / 28.0f);
    const float inv_sy = (by1 - by0) * (1.0f / 28.0f);

    // nonzero support: xs in (-1,28)  <=>  x in (xlo, xhi), row-independent
    const float xlo = bx0 - 0.5f - 0.5f * inv_sx;
    const float xhi = bx0 - 0.5f + 28.5f * inv_sx;
    const float ylo = by0 - 0.5f - 0.5f * inv_sy;
    const float yhi = by0 - 0.5f + 28.5f * inv_sy;

    const int clo = max(0, (int)floorf(xlo));
    const int chi = min(OUT_W, (int)ceilf(xhi) + 1);
    const int rlo = max(0, (int)floorf(ylo));
    const int rhi = min(OUT_H, (int)ceilf(yhi) + 1);

    const int r0 = rlo + blockIdx.y * ROWS_PER_TILE;
    if (r0 >= rhi) return;
    const int r1 = min(r0 + ROWS_PER_TILE, rhi);

    // zero-padded LDS mask at [1..28][1..28]
    __shared__ float sm[MASK_HW + 2][MASK_HW + 5];        // 30 x 33
    for (int i = tid; i < (MASK_HW + 2) * (MASK_HW + 5); i += 256)
        ((float*)sm)[i] = 0.0f;
    __syncthreads();
    const float* mptr = masks + (size_t)n * (MASK_HW * MASK_HW);
    for (int i = tid; i < MASK_HW * MASK_HW; i += 256) {
        const int r = i / MASK_HW;
        const int c = i - r * MASK_HW;
        sm[r + 1][c + 1] = mptr[i];
    }
    __syncthreads();

    float* outn = out + (size_t)n * (OUT_H * OUT_W);

    for (int row = r0; row < r1; ++row) {
        const float ys = ((float)row + 0.5f - by0) * syf - 0.5f;
        if (ys <= -1.0f || ys >= 28.0f) continue;
        const float y0f = floorf(ys);
        const int   y0i = (int)y0f;                       // [-1, 27]
        const float wy1 = ys - y0f;
        const float wy0 = 1.0f - wy1;
        const float* rA = &sm[y0i + 1][0];
        const float* rB = &sm[y0i + 2][0];

        for (int c = clo + tid; c < chi; c += 256) {
            const float xs = ((float)c + 0.5f - bx0) * sxf - 0.5f;
            float val = 0.0f;
            if (xs > -1.0f && xs < 28.0f) {
                const float x0f = floorf(xs);
                const int   x0i = (int)x0f;               // [-1, 27]
                const float wx1 = xs - x0f;
                const float wx0 = 1.0f - wx1;
                val = wy0 * (wx0 * rA[x0i + 1] + wx1 * rA[x0i + 2]) +
                      wy1 * (wx0 * rB[x0i + 1] + wx1 * rB[x0i + 2]);
            }
            outn[(size_t)row * OUT_W + c] = val;
        }
    }
}

extern "C" void kernel_launch(void* const* d_in, const int* in_sizes, int n_in,
                              void* d_out, int out_size, void* d_ws, size_t ws_size,
                              hipStream_t stream) {
    const float* masks = (const float*)d_in[0];   // [100,1,28,28] fp32
    const float* boxes = (const float*)d_in[1];   // [100,4] fp32
    float* out = (float*)d_out;                   // [100,1,512,512] fp32

    // 26,214,400 floats = 6,553,600 float4 = 25600 blocks x 256 threads exactly
    zero_fill_kernel<<<dim3(25600), dim3(256), 0, stream>>>((f32x4*)out);

    paste_box_kernel<<<dim3(N_INST, 17), dim3(256), 0, stream>>>(masks, boxes, out);
}

// Round 6
// 117.899 us; speedup vs baseline: 1.0790x; 1.0790x over previous
//
#include <hip/hip_runtime.h>

#define MASK_HW 28
#define OUT_H 512
#define OUT_W 512
#define N_INST 100

typedef __attribute__((ext_vector_type(4))) float f32x4;

// ---------------------------------------------------------------------------
// Single fused kernel, memset-shaped: exactly one float4 store per thread,
// no LDS, no barriers, no loops. 256 blocks per instance (2 rows per block,
// 128 float4 per row). The ~92% of waves whose row is outside the box's
// y-support reduce to: decode indices + uniform compare + store zeros.
// In-range waves do bilinear with weight-zeroed boundary taps, reading the
// 28x28 mask directly through L1/L2 (masks total 0.3 MB, L2-resident).
// ---------------------------------------------------------------------------
__global__ __launch_bounds__(256) void fused_paste_kernel(
    const float* __restrict__ masks,   // [N,1,28,28]
    const float* __restrict__ boxes,   // [N,4]
    f32x4* __restrict__ out)           // [N,512,512/4]
{
    const int bid = blockIdx.x;
    const int n   = bid >> 8;                 // instance: 256 blocks each
    const int idx = ((bid & 255) << 8) | threadIdx.x;  // f4 index in instance
    const int row = idx >> 7;                 // 128 float4 per row
    const int xq  = idx & 127;

    f32x4* outp = out + ((size_t)n << 16) + idx;

    // scalar (wave-uniform) box fetch
    const float by0 = boxes[4 * n + 1];
    const float by1 = boxes[4 * n + 3] + 1e-5f;
    const float syf = 28.0f / (by1 - by0);
    const float ys  = ((float)row + 0.5f - by0) * syf - 0.5f;

    if (ys <= -1.0f || ys >= 28.0f) {         // wave-uniform (row per half-wave pair)
        *outp = (f32x4)0.0f;
        return;
    }

    const float bx0 = boxes[4 * n + 0];
    const float bx1 = boxes[4 * n + 2] + 1e-5f;
    const float sxf = 28.0f / (bx1 - bx0);

    const float y0f = floorf(ys);
    const int   y0i = (int)y0f;               // [-1, 27]
    const float wy1 = ys - y0f;
    const float wy0 = 1.0f - wy1;
    const float wyA = (y0i >= 0)  ? wy0 : 0.0f;
    const float wyB = (y0i <= 26) ? wy1 : 0.0f;
    const int   yA  = max(y0i, 0);
    const int   yB  = min(y0i + 1, MASK_HW - 1);
    const float* mrowA = masks + (size_t)n * (MASK_HW * MASK_HW) + yA * MASK_HW;
    const float* mrowB = masks + (size_t)n * (MASK_HW * MASK_HW) + yB * MASK_HW;

    const float xbase = (float)(xq * 4) + 0.5f - bx0;
    float res[4];
    #pragma unroll
    for (int j = 0; j < 4; ++j) {
        const float xs = (xbase + (float)j) * sxf - 0.5f;
        float v = 0.0f;
        if (xs > -1.0f && xs < 28.0f) {
            const float x0f = floorf(xs);
            const int   x0i = (int)x0f;       // [-1, 27]
            const float wx1 = xs - x0f;
            const float wx0 = 1.0f - wx1;
            const float wxA = (x0i >= 0)  ? wx0 : 0.0f;
            const float wxB = (x0i <= 26) ? wx1 : 0.0f;
            const int   xA  = max(x0i, 0);
            const int   xB  = min(x0i + 1, MASK_HW - 1);
            v = wyA * (wxA * mrowA[xA] + wxB * mrowA[xB]) +
                wyB * (wxA * mrowB[xA] + wxB * mrowB[xB]);
        }
        res[j] = v;
    }
    f32x4 o; o.x = res[0]; o.y = res[1]; o.z = res[2]; o.w = res[3];
    *outp = o;
}

extern "C" void kernel_launch(void* const* d_in, const int* in_sizes, int n_in,
                              void* d_out, int out_size, void* d_ws, size_t ws_size,
                              hipStream_t stream) {
    const float* masks = (const float*)d_in[0];   // [100,1,28,28] fp32
    const float* boxes = (const float*)d_in[1];   // [100,4] fp32

    // 100 instances x 256 blocks = 25600 blocks; one float4 per thread exactly
    fused_paste_kernel<<<dim3(N_INST * 256), dim3(256), 0, stream>>>(
        masks, boxes, (f32x4*)d_out);
}